// Round 8
// baseline (257.624 us; speedup 1.0000x reference)
//
#include <hip/hip_runtime.h>
#include <hip/hip_bf16.h>

typedef __attribute__((ext_vector_type(8))) short short8;   // 8 bf16 = 4 VGPR (MFMA A/B frag)
typedef __attribute__((ext_vector_type(4))) float f32x4;    // MFMA C/D frag

__device__ __forceinline__ unsigned short f2bf(float f) {
    union { __hip_bfloat16 h; unsigned short u; } cv;
    cv.h = __float2bfloat16(f);   // RNE
    return cv.u;
}

// jax.nn.gelu(approximate=True): 0.5x(1+tanh(sqrt(2/pi)(x+0.044715x^3))) == x*e/(e+1), e=exp(2*inner)
__device__ __forceinline__ float gelu_t(float x) {
    float e = __expf(1.5957691216057308f * x * __builtin_fmaf(0.044715f, x * x, 1.0f));
    return x * (e / (e + 1.0f));
}

__device__ __forceinline__ void gload_lds16(const void* g, void* l) {
    __builtin_amdgcn_global_load_lds((const __attribute__((address_space(1))) unsigned int*)g,
                                     (__attribute__((address_space(3))) unsigned int*)l, 16, 0, 0);
}

// XOR swizzle key for 64B LDS slices, row stride 64B (conflicts==0 measured R3)
__device__ __forceinline__ int swzkey(int r) { return ((r >> 1) & 3) << 4; }

// ---------------------------------------------------------------------------
// Transpose + f32->bf16 + pre-swizzle for We, Wd, W2 (one launch). R5-verified:
// out[n][k], 64B k-slices, inner byte ^= swzkey(n).
// ---------------------------------------------------------------------------
__global__ __launch_bounds__(256) void transpose_all(const float* __restrict__ W1,
                                                     const float* __restrict__ W2,
                                                     unsigned short* __restrict__ Wet,
                                                     unsigned short* __restrict__ Wdt,
                                                     unsigned short* __restrict__ W2t) {
    int z = blockIdx.z;
    if (z < 2 && blockIdx.y >= 8) return;      // We/Wd have N=512
    const float* in = (z == 0) ? W1 : (z == 1) ? (W1 + 512 * 512) : W2;
    unsigned short* out = (z == 0) ? Wet : (z == 1) ? Wdt : W2t;
    int N = (z == 2) ? 1024 : 512;

    __shared__ float tile[64][65];
    int k0 = blockIdx.x * 64, n0 = blockIdx.y * 64;
    int t = threadIdx.x;
    int c = t & 63, r0 = t >> 6;
#pragma unroll
    for (int i = 0; i < 16; i++) {
        int r = r0 + i * 4;
        tile[r][c] = in[(size_t)(k0 + r) * N + n0 + c];
    }
    __syncthreads();
    int kk = t & 15;
    int nl0 = t >> 4;
#pragma unroll
    for (int i = 0; i < 4; i++) {
        int nl = nl0 + i * 16;
        int n  = n0 + nl;
        unsigned short b0 = f2bf(tile[kk * 4 + 0][nl]);
        unsigned short b1 = f2bf(tile[kk * 4 + 1][nl]);
        unsigned short b2 = f2bf(tile[kk * 4 + 2][nl]);
        unsigned short b3 = f2bf(tile[kk * 4 + 3][nl]);
        uint2 v;
        v.x = (unsigned)b0 | ((unsigned)b1 << 16);
        v.y = (unsigned)b2 | ((unsigned)b3 << 16);
        int byte_in_chunk = kk * 8;
        int slice = byte_in_chunk & ~63;
        int off   = (byte_in_chunk & 63) ^ swzkey(n);
        size_t obyte = (size_t)n * 1024 + (size_t)k0 * 2 + slice + off;
        *(uint2*)((char*)out + obyte) = v;
    }
}

// ---------------------------------------------------------------------------
// he/hd GEMM (one launch): C[M][512] = A[M][512] @ Bt^T (+bias). (verified R3-R7)
// ---------------------------------------------------------------------------
__global__ __launch_bounds__(256, 2) void gemm_small(const float* __restrict__ enc,
                                                     const float* __restrict__ dec,
                                                     const unsigned short* __restrict__ Wet,
                                                     const unsigned short* __restrict__ Wdt,
                                                     const float* __restrict__ b1,
                                                     float* __restrict__ he,
                                                     float* __restrict__ hd) {
    bool isEnc = blockIdx.x < 8;
    const float* A = isEnc ? enc : dec;
    const unsigned short* Bt = isEnc ? Wet : Wdt;
    const float* bias = isEnc ? b1 : nullptr;
    float* C = isEnc ? he : hd;
    size_t m0 = (size_t)(isEnc ? blockIdx.x : blockIdx.x - 8) * 128;

    __shared__ alignas(16) unsigned short As[128 * 32];
    __shared__ alignas(16) unsigned short Bs[128 * 32];
    int t = threadIdx.x;
    int n0 = blockIdx.y * 128;
    int lane = t & 63, w = t >> 6;
    int wm = w >> 1, wn = w & 1;
    int rA = t >> 3, cg = t & 7;
    f32x4 acc[4][4] = {};

    for (int kt = 0; kt < 16; ++kt) {
        int k0 = kt * 32;
        __syncthreads();
#pragma unroll
        for (int p = 0; p < 4; p++) {
            int r = rA + p * 32;
            f32x4 v = *(const f32x4*)&A[(m0 + r) * 512 + k0 + cg * 4];
            uint2 pk;
            pk.x = (unsigned)f2bf(v.x) | ((unsigned)f2bf(v.y) << 16);
            pk.y = (unsigned)f2bf(v.z) | ((unsigned)f2bf(v.w) << 16);
            int off = (cg * 8) ^ swzkey(r);
            *(uint2*)((char*)As + r * 64 + off) = pk;
        }
#pragma unroll
        for (int j = 0; j < 2; j++) {
            int ibyte = w * 1024 + j * 4096;
            int lb = ibyte + lane * 16;
            int row = lb >> 6, colb = lb & 63;
            const char* src = (const char*)Bt + (size_t)(n0 + row) * 1024 + k0 * 2 + colb;
            gload_lds16(src, (char*)Bs + ibyte);
        }
        __syncthreads();
        short8 af[4], bf[4];
#pragma unroll
        for (int mi = 0; mi < 4; mi++) {
            int r = wm * 64 + mi * 16 + (lane & 15);
            int off = ((lane >> 4) * 16) ^ swzkey(r);
            af[mi] = *(const short8*)((const char*)As + r * 64 + off);
        }
#pragma unroll
        for (int ni = 0; ni < 4; ni++) {
            int n = wn * 64 + ni * 16 + (lane & 15);
            int off = ((lane >> 4) * 16) ^ swzkey(n);
            bf[ni] = *(const short8*)((const char*)Bs + n * 64 + off);
        }
#pragma unroll
        for (int mi = 0; mi < 4; mi++)
#pragma unroll
            for (int ni = 0; ni < 4; ni++)
                acc[mi][ni] = __builtin_amdgcn_mfma_f32_16x16x32_bf16(af[mi], bf[ni], acc[mi][ni], 0, 0, 0);
    }
#pragma unroll
    for (int mi = 0; mi < 4; mi++) {
        int row = wm * 64 + mi * 16 + ((lane >> 4) << 2);
#pragma unroll
        for (int ni = 0; ni < 4; ni++) {
            int col = n0 + wn * 64 + ni * 16 + (lane & 15);
            float bv = bias ? bias[col] : 0.0f;
#pragma unroll
            for (int q = 0; q < 4; q++)
                C[(m0 + row + q) * 512 + col] = acc[mi][ni][q] + bv;
        }
    }
}

// ---------------------------------------------------------------------------
// Fused joint, m201-shaped: out[m][v] = gelu(he+hd) @ W2.
// BM=256 BN=256 BK=64, 512 thr (8 waves 2m x 4n, wave 128x64, acc[8][4]).
// 8 K-tiles; ONE barrier per tile; 4 phases/tile, each: {producer work
// (B-stage / h-load / gelu ds_write for tile t+1)} + {frag reads} + {16 MFMA
// under setprio}. Counted waits: vmcnt(0) only at the tile boundary, where
// all in-flight stages are >=2 phases old. LDS 128KB: A[2][2sl][256][64B],
// B[2][2sl][256][64B] — R5's proven 64B-slice XOR layout (conflicts==0).
// ---------------------------------------------------------------------------
__global__ __launch_bounds__(512, 1) void joint_fused(const float* __restrict__ he,
                                                      const float* __restrict__ hd,
                                                      const unsigned short* __restrict__ W2t,
                                                      float* __restrict__ out) {
    __shared__ alignas(16) char lds[131072];
    constexpr int BB = 65536;                   // B region base
    int t = threadIdx.x;
    int lane = t & 63, w = t >> 6;
    int wm = w >> 2, wn = w & 3;                // 2m x 4n
    int bx = blockIdx.x;                        // 0..383 (384 % 8 == 0 -> bijective XCD swz)
    int mt = (bx & 7) * 48 + (bx >> 3);
    size_t m0 = (size_t)mt * 256;
    int n0 = blockIdx.y * 256;

    // ---- A-gen addressing: 4 passes; pass p covers rows rT+64p; 8 k's at cg*8
    int rT = t >> 3, cg = t & 7;
    const float* eP[4];
    const float* dP[4];
    int aw[4];
#pragma unroll
    for (int p = 0; p < 4; p++) {
        int r = rT + p * 64;
        int mrow = (int)m0 + r;
        int tI = mrow / 96, u = mrow - tI * 96;
        eP[p] = he + (size_t)tI * 512 + cg * 8;
        dP[p] = hd + (size_t)((tI >> 8) * 96 + u) * 512 + cg * 8;
        aw[p] = (cg >> 2) * 16384 + r * 64 + (((cg & 3) * 16) ^ swzkey(r));
    }
    // ---- B staging: 4 insts/wave/tile; waves 0-3 fill sl0, 4-7 fill sl1.
    // W2t is pre-swizzled, LDS dest linear -> identity source inner (rule 21, R5-proven)
    const char* bsrc[4];
#pragma unroll
    for (int j = 0; j < 4; j++) {
        int nl = (w & 3) * 64 + j * 16 + (lane >> 2);
        bsrc[j] = (const char*)W2t + (size_t)(n0 + nl) * 1024 + (w >> 2) * 64 + (lane & 3) * 16;
    }
    // ---- fragment byte offsets (within a [256][64B] slab)
    int l15 = lane & 15, lg = lane >> 4;
    int aO[8], bO[4];
#pragma unroll
    for (int mi = 0; mi < 8; mi++) {
        int r = wm * 128 + mi * 16 + l15;
        aO[mi] = r * 64 + ((lg * 16) ^ swzkey(r));
    }
#pragma unroll
    for (int ni = 0; ni < 4; ni++) {
        int n = wn * 64 + ni * 16 + l15;
        bO[ni] = n * 64 + ((lg * 16) ^ swzkey(n));
    }

    f32x4 acc[8][4] = {};
    f32x4 se0, se1, sd0, sd1;                   // single h-reg slot (16 VGPR), rotated

#define HL(p, t1)  do { \
        se0 = *(const f32x4*)(eP[p] + (t1) * 64); \
        se1 = *(const f32x4*)(eP[p] + (t1) * 64 + 4); \
        sd0 = *(const f32x4*)(dP[p] + (t1) * 64); \
        sd1 = *(const f32x4*)(dP[p] + (t1) * 64 + 4); } while (0)

#define GEN(p, buf) do { uint4 pk; \
        pk.x = (unsigned)f2bf(gelu_t(se0.x + sd0.x)) | ((unsigned)f2bf(gelu_t(se0.y + sd0.y)) << 16); \
        pk.y = (unsigned)f2bf(gelu_t(se0.z + sd0.z)) | ((unsigned)f2bf(gelu_t(se0.w + sd0.w)) << 16); \
        pk.z = (unsigned)f2bf(gelu_t(se1.x + sd1.x)) | ((unsigned)f2bf(gelu_t(se1.y + sd1.y)) << 16); \
        pk.w = (unsigned)f2bf(gelu_t(se1.z + sd1.z)) | ((unsigned)f2bf(gelu_t(se1.w + sd1.w)) << 16); \
        *(uint4*)(lds + (buf) * 32768 + aw[p]) = pk; } while (0)

#define STAGE(buf, t1, j) \
        gload_lds16(bsrc[j] + (size_t)(t1) * 128, lds + BB + (buf) * 32768 + w * 4096 + (j) * 1024)

    // ---- prologue: tile 0 fully staged/generated
    STAGE(0, 0, 0); STAGE(0, 0, 1); STAGE(0, 0, 2); STAGE(0, 0, 3);
    HL(0, 0); GEN(0, 0);
    HL(1, 0); GEN(1, 0);
    HL(2, 0); GEN(2, 0);
    HL(3, 0); GEN(3, 0);
    asm volatile("s_waitcnt lgkmcnt(0)" ::: "memory");
    asm volatile("s_waitcnt vmcnt(0)" ::: "memory");
    __builtin_amdgcn_sched_barrier(0);
    __builtin_amdgcn_s_barrier();
    __builtin_amdgcn_sched_barrier(0);

#pragma unroll
    for (int tt = 0; tt < 8; ++tt) {
        const int cur = tt & 1, nxt = cur ^ 1;
        const char* Ab = lds + cur * 32768;
        const char* Bb = lds + BB + cur * 32768;
        const bool pre = (tt < 7);
        short8 a[8], b0, b1, b2, b3;
        // ---- phase 0: stage j0/j1, h-load pass0; MFMA kk0 x ni01
        if (pre) { STAGE(nxt, tt + 1, 0); STAGE(nxt, tt + 1, 1); HL(0, tt + 1); }
#pragma unroll
        for (int mi = 0; mi < 8; mi++) a[mi] = *(const short8*)(Ab + aO[mi]);
        b0 = *(const short8*)(Bb + bO[0]);
        b1 = *(const short8*)(Bb + bO[1]);
        __builtin_amdgcn_s_setprio(1);
#pragma unroll
        for (int mi = 0; mi < 8; mi++) {
            acc[mi][0] = __builtin_amdgcn_mfma_f32_16x16x32_bf16(a[mi], b0, acc[mi][0], 0, 0, 0);
            acc[mi][1] = __builtin_amdgcn_mfma_f32_16x16x32_bf16(a[mi], b1, acc[mi][1], 0, 0, 0);
        }
        __builtin_amdgcn_s_setprio(0);
        // ---- phase 1: gelu pass0, h-load pass1; MFMA kk0 x ni23
        if (pre) { GEN(0, nxt); HL(1, tt + 1); }
        b2 = *(const short8*)(Bb + bO[2]);
        b3 = *(const short8*)(Bb + bO[3]);
        __builtin_amdgcn_s_setprio(1);
#pragma unroll
        for (int mi = 0; mi < 8; mi++) {
            acc[mi][2] = __builtin_amdgcn_mfma_f32_16x16x32_bf16(a[mi], b2, acc[mi][2], 0, 0, 0);
            acc[mi][3] = __builtin_amdgcn_mfma_f32_16x16x32_bf16(a[mi], b3, acc[mi][3], 0, 0, 0);
        }
        __builtin_amdgcn_s_setprio(0);
        // ---- phase 2: stage j2/j3, gelu pass1, h-load pass2; MFMA kk1 x ni01
        if (pre) { STAGE(nxt, tt + 1, 2); STAGE(nxt, tt + 1, 3); GEN(1, nxt); HL(2, tt + 1); }
#pragma unroll
        for (int mi = 0; mi < 8; mi++) a[mi] = *(const short8*)(Ab + 16384 + aO[mi]);
        b0 = *(const short8*)(Bb + 16384 + bO[0]);
        b1 = *(const short8*)(Bb + 16384 + bO[1]);
        __builtin_amdgcn_s_setprio(1);
#pragma unroll
        for (int mi = 0; mi < 8; mi++) {
            acc[mi][0] = __builtin_amdgcn_mfma_f32_16x16x32_bf16(a[mi], b0, acc[mi][0], 0, 0, 0);
            acc[mi][1] = __builtin_amdgcn_mfma_f32_16x16x32_bf16(a[mi], b1, acc[mi][1], 0, 0, 0);
        }
        __builtin_amdgcn_s_setprio(0);
        // ---- phase 3: gelu pass2, h-load pass3; MFMA kk1 x ni23
        if (pre) { GEN(2, nxt); HL(3, tt + 1); }
        b2 = *(const short8*)(Bb + 16384 + bO[2]);
        b3 = *(const short8*)(Bb + 16384 + bO[3]);
        __builtin_amdgcn_s_setprio(1);
#pragma unroll
        for (int mi = 0; mi < 8; mi++) {
            acc[mi][2] = __builtin_amdgcn_mfma_f32_16x16x32_bf16(a[mi], b2, acc[mi][2], 0, 0, 0);
            acc[mi][3] = __builtin_amdgcn_mfma_f32_16x16x32_bf16(a[mi], b3, acc[mi][3], 0, 0, 0);
        }
        __builtin_amdgcn_s_setprio(0);
        // ---- tile boundary: gelu pass3, then the ONLY barrier of the tile
        if (pre) {
            GEN(3, nxt);
            asm volatile("s_waitcnt lgkmcnt(0)" ::: "memory");   // A(nxt) writes + own reads done
            __builtin_amdgcn_sched_barrier(0);
            asm volatile("s_waitcnt vmcnt(0)" ::: "memory");     // B(nxt) landed (issued >=2 phases ago)
            __builtin_amdgcn_sched_barrier(0);
            __builtin_amdgcn_s_barrier();
            __builtin_amdgcn_sched_barrier(0);
        }
    }
#undef HL
#undef GEN
#undef STAGE

    // ---- epilogue: LDS dead -> per-wave pad (16 rows x 68 f32, 4352B/wave),
    // then 16B/lane NT stores (256B contiguous per 16-lane group)
    asm volatile("s_waitcnt lgkmcnt(0)" ::: "memory");
    __builtin_amdgcn_sched_barrier(0);
    __builtin_amdgcn_s_barrier();
    __builtin_amdgcn_sched_barrier(0);

    char* ep = lds + w * 4352;
#pragma unroll
    for (int mi = 0; mi < 8; mi++) {
#pragma unroll
        for (int ni = 0; ni < 4; ni++)
#pragma unroll
            for (int q = 0; q < 4; q++)
                *(float*)(ep + (lg * 4 + q) * 272 + (ni * 16 + l15) * 4) = acc[mi][ni][q];
        asm volatile("s_waitcnt lgkmcnt(0)" ::: "memory");
        __builtin_amdgcn_sched_barrier(0);
#pragma unroll
        for (int it = 0; it < 4; it++) {
            int r = it * 4 + lg;
            f32x4 v = *(const f32x4*)(ep + r * 272 + l15 * 16);
            size_t row = m0 + wm * 128 + mi * 16 + r;
            float* o = out + row * 1024 + n0 + wn * 64 + l15 * 4;
            __builtin_nontemporal_store(v, (f32x4*)o);
        }
        asm volatile("s_waitcnt lgkmcnt(0)" ::: "memory");   // reads done before next mi overwrite
        __builtin_amdgcn_sched_barrier(0);
    }
}

extern "C" void kernel_launch(void* const* d_in, const int* in_sizes, int n_in,
                              void* d_out, int out_size, void* d_ws, size_t ws_size,
                              hipStream_t stream) {
    const float* enc = (const float*)d_in[0];   // (4,256,512)
    const float* dec = (const float*)d_in[1];   // (4,96,512)
    const float* W1  = (const float*)d_in[2];   // (1024,512)
    const float* b1  = (const float*)d_in[3];   // (512,)
    const float* W2  = (const float*)d_in[4];   // (512,1024)
    float* out = (float*)d_out;                 // (4,256,96,1024) f32

    char* ws = (char*)d_ws;
    float* he = (float*)(ws);                               // 1024x512 f32 (b1 folded)
    float* hd = (float*)(ws + 2097152);                     //  384x512 f32
    unsigned short* Wet = (unsigned short*)(ws + 2883584);  // 512x512 bf16 swz
    unsigned short* Wdt = (unsigned short*)(ws + 3407872);  // 512x512 bf16 swz
    unsigned short* W2t = (unsigned short*)(ws + 3932160);  // 1024x512 bf16 swz

    transpose_all<<<dim3(8, 16, 3), 256, 0, stream>>>(W1, W2, Wet, Wdt, W2t);
    gemm_small<<<dim3(11, 4), 256, 0, stream>>>(enc, dec, Wet, Wdt, b1, he, hd);
    joint_fused<<<dim3(384, 4), 512, 0, stream>>>(he, hd, W2t, out);
}

// Round 9
// 189.646 us; speedup vs baseline: 1.3584x; 1.3584x over previous
//
#include <hip/hip_runtime.h>
#include <hip/hip_bf16.h>

typedef __attribute__((ext_vector_type(8))) short short8;   // 8 bf16 = 4 VGPR (MFMA A/B frag)
typedef __attribute__((ext_vector_type(4))) float f32x4;    // MFMA C/D frag

__device__ __forceinline__ unsigned short f2bf(float f) {
    union { __hip_bfloat16 h; unsigned short u; } cv;
    cv.h = __float2bfloat16(f);   // RNE
    return cv.u;
}

// jax.nn.gelu(approximate=True): 0.5x(1+tanh(sqrt(2/pi)(x+0.044715x^3))) == x*e/(e+1), e=exp(2*inner)
__device__ __forceinline__ float gelu_t(float x) {
    float e = __expf(1.5957691216057308f * x * __builtin_fmaf(0.044715f, x * x, 1.0f));
    return x * (e / (e + 1.0f));
}

__device__ __forceinline__ void gload_lds16(const void* g, void* l) {
    __builtin_amdgcn_global_load_lds((const __attribute__((address_space(1))) unsigned int*)g,
                                     (__attribute__((address_space(3))) unsigned int*)l, 16, 0, 0);
}

// XOR swizzle key for 64B LDS slices (conflicts==0 measured R3/R5)
__device__ __forceinline__ int swzkey(int r) { return ((r >> 1) & 3) << 4; }

// ---------------------------------------------------------------------------
// Transpose + f32->bf16 + pre-swizzle for We, Wd, W2 (one launch). (verified R3-R8)
// ---------------------------------------------------------------------------
__global__ __launch_bounds__(256) void transpose_all(const float* __restrict__ W1,
                                                     const float* __restrict__ W2,
                                                     unsigned short* __restrict__ Wet,
                                                     unsigned short* __restrict__ Wdt,
                                                     unsigned short* __restrict__ W2t) {
    int z = blockIdx.z;
    if (z < 2 && blockIdx.y >= 8) return;      // We/Wd have N=512
    const float* in = (z == 0) ? W1 : (z == 1) ? (W1 + 512 * 512) : W2;
    unsigned short* out = (z == 0) ? Wet : (z == 1) ? Wdt : W2t;
    int N = (z == 2) ? 1024 : 512;

    __shared__ float tile[64][65];
    int k0 = blockIdx.x * 64, n0 = blockIdx.y * 64;
    int t = threadIdx.x;
    int c = t & 63, r0 = t >> 6;
#pragma unroll
    for (int i = 0; i < 16; i++) {
        int r = r0 + i * 4;
        tile[r][c] = in[(size_t)(k0 + r) * N + n0 + c];
    }
    __syncthreads();
    int kk = t & 15;
    int nl0 = t >> 4;
#pragma unroll
    for (int i = 0; i < 4; i++) {
        int nl = nl0 + i * 16;
        int n  = n0 + nl;
        unsigned short b0 = f2bf(tile[kk * 4 + 0][nl]);
        unsigned short b1 = f2bf(tile[kk * 4 + 1][nl]);
        unsigned short b2 = f2bf(tile[kk * 4 + 2][nl]);
        unsigned short b3 = f2bf(tile[kk * 4 + 3][nl]);
        uint2 v;
        v.x = (unsigned)b0 | ((unsigned)b1 << 16);
        v.y = (unsigned)b2 | ((unsigned)b3 << 16);
        int byte_in_chunk = kk * 8;
        int slice = byte_in_chunk & ~63;
        int off   = (byte_in_chunk & 63) ^ swzkey(n);
        size_t obyte = (size_t)n * 1024 + (size_t)k0 * 2 + slice + off;
        *(uint2*)((char*)out + obyte) = v;
    }
}

// ---------------------------------------------------------------------------
// he/hd GEMM (one launch): C[M][512] = A[M][512] @ Bt^T (+bias). (verified R3-R8)
// ---------------------------------------------------------------------------
__global__ __launch_bounds__(256, 2) void gemm_small(const float* __restrict__ enc,
                                                     const float* __restrict__ dec,
                                                     const unsigned short* __restrict__ Wet,
                                                     const unsigned short* __restrict__ Wdt,
                                                     const float* __restrict__ b1,
                                                     float* __restrict__ he,
                                                     float* __restrict__ hd) {
    bool isEnc = blockIdx.x < 8;
    const float* A = isEnc ? enc : dec;
    const unsigned short* Bt = isEnc ? Wet : Wdt;
    const float* bias = isEnc ? b1 : nullptr;
    float* C = isEnc ? he : hd;
    size_t m0 = (size_t)(isEnc ? blockIdx.x : blockIdx.x - 8) * 128;

    __shared__ alignas(16) unsigned short As[128 * 32];
    __shared__ alignas(16) unsigned short Bs[128 * 32];
    int t = threadIdx.x;
    int n0 = blockIdx.y * 128;
    int lane = t & 63, w = t >> 6;
    int wm = w >> 1, wn = w & 1;
    int rA = t >> 3, cg = t & 7;
    f32x4 acc[4][4] = {};

    for (int kt = 0; kt < 16; ++kt) {
        int k0 = kt * 32;
        __syncthreads();
#pragma unroll
        for (int p = 0; p < 4; p++) {
            int r = rA + p * 32;
            f32x4 v = *(const f32x4*)&A[(m0 + r) * 512 + k0 + cg * 4];
            uint2 pk;
            pk.x = (unsigned)f2bf(v.x) | ((unsigned)f2bf(v.y) << 16);
            pk.y = (unsigned)f2bf(v.z) | ((unsigned)f2bf(v.w) << 16);
            int off = (cg * 8) ^ swzkey(r);
            *(uint2*)((char*)As + r * 64 + off) = pk;
        }
#pragma unroll
        for (int j = 0; j < 2; j++) {
            int ibyte = w * 1024 + j * 4096;
            int lb = ibyte + lane * 16;
            int row = lb >> 6, colb = lb & 63;
            const char* src = (const char*)Bt + (size_t)(n0 + row) * 1024 + k0 * 2 + colb;
            gload_lds16(src, (char*)Bs + ibyte);
        }
        __syncthreads();
        short8 af[4], bf[4];
#pragma unroll
        for (int mi = 0; mi < 4; mi++) {
            int r = wm * 64 + mi * 16 + (lane & 15);
            int off = ((lane >> 4) * 16) ^ swzkey(r);
            af[mi] = *(const short8*)((const char*)As + r * 64 + off);
        }
#pragma unroll
        for (int ni = 0; ni < 4; ni++) {
            int n = wn * 64 + ni * 16 + (lane & 15);
            int off = ((lane >> 4) * 16) ^ swzkey(n);
            bf[ni] = *(const short8*)((const char*)Bs + n * 64 + off);
        }
#pragma unroll
        for (int mi = 0; mi < 4; mi++)
#pragma unroll
            for (int ni = 0; ni < 4; ni++)
                acc[mi][ni] = __builtin_amdgcn_mfma_f32_16x16x32_bf16(af[mi], bf[ni], acc[mi][ni], 0, 0, 0);
    }
#pragma unroll
    for (int mi = 0; mi < 4; mi++) {
        int row = wm * 64 + mi * 16 + ((lane >> 4) << 2);
#pragma unroll
        for (int ni = 0; ni < 4; ni++) {
            int col = n0 + wn * 64 + ni * 16 + (lane & 15);
            float bv = bias ? bias[col] : 0.0f;
#pragma unroll
            for (int q = 0; q < 4; q++)
                C[(m0 + row + q) * 512 + col] = acc[mi][ni][q] + bv;
        }
    }
}

// ---------------------------------------------------------------------------
// Fused joint: out[m][v] = gelu(he[t(m)]+hd[b,u(m)]) @ W2.
// R5 structure (best measured: joint ~165us, conflicts==0) with ONE change:
// wave decomposition 2m x 4n -> 1m x 8n (wave = 64 rows x 64 cols, acc[4][4]).
// B-frags now read once each (was twice); LDS reads/step 10 -> 8 per wave.
// Everything else verbatim: BM=64 BN=512 BK=32, dbuf A+B, counted vmcnt(2),
// one barrier/step, LDS-pad epilogue with NT 16B stores.
// ---------------------------------------------------------------------------
__global__ __launch_bounds__(512, 4) void joint_fused(const float* __restrict__ he,
                                                      const float* __restrict__ hd,
                                                      const unsigned short* __restrict__ W2t,
                                                      float* __restrict__ out) {
    __shared__ alignas(16) char lds[73728];
    // carve: As[0]=0, As[1]=4096, Bs[0]=8192, Bs[1]=40960   (A 4KB x2, B 32KB x2)
    int t = threadIdx.x;
    int lane = t & 63, w = t >> 6;
    int bx = blockIdx.x;                   // 0..1535, XCD-swizzle (1536 % 8 == 0 -> bijective)
    int mt = (bx & 7) * 192 + (bx >> 3);
    size_t m0 = (size_t)mt * 64;
    int n0 = blockIdx.y * 512;

    // ---- A-gen mapping (fixed per thread): row rA = t>>3, 4 k's at cg*4 (verified R5)
    int rA = t >> 3, cg = t & 7;
    int mrow = (int)m0 + rA;
    int tI = mrow / 96;                    // b*256+t index into he (0..1023)
    int u  = mrow - tI * 96;
    const float* eP = he + (size_t)tI * 512 + cg * 4;
    const float* dP = hd + (size_t)((tI >> 8) * 96 + u) * 512 + cg * 4;
    int aoff = rA * 64 + ((cg * 8) ^ swzkey(rA));

    // ---- B staging: wave w covers Bs rows [w*64, w*64+64), 4 x 1KB insts (verified R5)
    const char* bSrc[4];
#pragma unroll
    for (int i = 0; i < 4; i++) {
        int row = w * 64 + i * 16 + (lane >> 2);
        bSrc[i] = (const char*)W2t + (size_t)(n0 + row) * 1024 + (lane & 3) * 16;
    }

    // ---- fragment byte offsets: 1m x 8n (wave owns all 64 rows, cols w*64..w*64+63)
    int l15 = lane & 15, lg = lane >> 4;
    int aOff[4], bOff[4];
#pragma unroll
    for (int mi = 0; mi < 4; mi++) {
        int r = mi * 16 + l15;
        aOff[mi] = r * 64 + ((lg * 16) ^ swzkey(r));
    }
#pragma unroll
    for (int ni = 0; ni < 4; ni++) {
        int n = w * 64 + ni * 16 + l15;
        bOff[ni] = 8192 + n * 64 + ((lg * 16) ^ swzkey(n));   // +Bs base
    }

    f32x4 acc[4][4] = {};
    f32x4 er[2], dr[2];                    // 2-slot rotation, static idx (unrolled)

#define LOADED(slot, kt)  do { \
        er[slot] = *(const f32x4*)(eP + (kt) * 32); \
        dr[slot] = *(const f32x4*)(dP + (kt) * 32); } while (0)

#define STAGE_B(buf, kt)  do { \
        _Pragma("unroll") \
        for (int i = 0; i < 4; i++) \
            gload_lds16(bSrc[i] + (kt) * 64, lds + 8192 + (buf) * 32768 + w * 4096 + i * 1024); } while (0)

#define GELU_A(buf, slot) do { \
        uint2 pk; \
        pk.x = (unsigned)f2bf(gelu_t(er[slot].x + dr[slot].x)) | \
               ((unsigned)f2bf(gelu_t(er[slot].y + dr[slot].y)) << 16); \
        pk.y = (unsigned)f2bf(gelu_t(er[slot].z + dr[slot].z)) | \
               ((unsigned)f2bf(gelu_t(er[slot].w + dr[slot].w)) << 16); \
        *(uint2*)(lds + (buf) * 4096 + aoff) = pk; } while (0)

    // ---- prologue: B(0) staged, regs tile0+tile1 in flight, A(0) written
    STAGE_B(0, 0);
    LOADED(0, 0);
    LOADED(1, 1);
    GELU_A(0, 0);                          // auto-wait drains slot-0 regs (B(0) older -> done)
    asm volatile("s_waitcnt lgkmcnt(0)" ::: "memory");
    asm volatile("s_waitcnt vmcnt(2)" ::: "memory");   // B(0) landed; tile-1 regs may fly
    __builtin_amdgcn_sched_barrier(0);
    __builtin_amdgcn_s_barrier();
    __builtin_amdgcn_sched_barrier(0);

#pragma unroll
    for (int kt = 0; kt < 16; ++kt) {
        const int cur = kt & 1, nxt = cur ^ 1;
        // issue next-tile staging and next-next reg loads first (fly under compute)
        if (kt < 15) STAGE_B(nxt, kt + 1);
        if (kt < 14) LOADED(cur, kt + 2);                 // slot kt&1 free: consumed last step
        if (kt < 15) GELU_A(nxt, nxt);                    // A(kt+1) from regs slot (kt+1)&1
        // fragments + MFMA from cur
        short8 a[4];
#pragma unroll
        for (int mi = 0; mi < 4; mi++) a[mi] = *(const short8*)(lds + cur * 4096 + aOff[mi]);
        __builtin_amdgcn_s_setprio(1);
#pragma unroll
        for (int ni = 0; ni < 4; ni++) {
            short8 b = *(const short8*)(lds + cur * 32768 + bOff[ni]);
#pragma unroll
            for (int mi = 0; mi < 4; mi++)
                acc[mi][ni] = __builtin_amdgcn_mfma_f32_16x16x32_bf16(a[mi], b, acc[mi][ni], 0, 0, 0);
        }
        __builtin_amdgcn_s_setprio(0);
        if (kt < 15) {
            // own frag reads + A(nxt) ds_write done; B(nxt) landed; reg loads stay in flight
            asm volatile("s_waitcnt lgkmcnt(0)" ::: "memory");
            __builtin_amdgcn_sched_barrier(0);
            if (kt < 14) asm volatile("s_waitcnt vmcnt(2)" ::: "memory");
            else         asm volatile("s_waitcnt vmcnt(0)" ::: "memory");
            __builtin_amdgcn_sched_barrier(0);
            __builtin_amdgcn_s_barrier();
            __builtin_amdgcn_sched_barrier(0);
        }
    }
#undef LOADED
#undef STAGE_B
#undef GELU_A

    // ---- epilogue via per-wave LDS pad: 16 rows x 76 f32 (4864 B/wave, 38.9KB tot)
    asm volatile("s_waitcnt lgkmcnt(0)" ::: "memory");
    __builtin_amdgcn_sched_barrier(0);
    __builtin_amdgcn_s_barrier();          // all waves done reading As/Bs -> LDS reusable
    __builtin_amdgcn_sched_barrier(0);

    char* ep = lds + w * 4864;
#pragma unroll
    for (int mi = 0; mi < 4; mi++) {
        // scatter acc into row-major pad (C/D layout: col=l15, row=lg*4+q); <=2-way banks
#pragma unroll
        for (int ni = 0; ni < 4; ni++)
#pragma unroll
            for (int q = 0; q < 4; q++)
                *(float*)(ep + (lg * 4 + q) * 304 + (ni * 16 + l15) * 4) = acc[mi][ni][q];
        asm volatile("s_waitcnt lgkmcnt(0)" ::: "memory");
        __builtin_amdgcn_sched_barrier(0);
        // read back contiguous rows, 16B/lane -> 256B contiguous per 16-lane group
#pragma unroll
        for (int it = 0; it < 4; it++) {
            int r = it * 4 + lg;
            f32x4 v = *(const f32x4*)(ep + r * 304 + l15 * 16);
            size_t row = m0 + mi * 16 + r;
            float* o = out + row * 1024 + n0 + w * 64 + l15 * 4;
            __builtin_nontemporal_store(v, (f32x4*)o);
        }
        asm volatile("s_waitcnt lgkmcnt(0)" ::: "memory");   // reads done before next mi overwrite
        __builtin_amdgcn_sched_barrier(0);
    }
}

extern "C" void kernel_launch(void* const* d_in, const int* in_sizes, int n_in,
                              void* d_out, int out_size, void* d_ws, size_t ws_size,
                              hipStream_t stream) {
    const float* enc = (const float*)d_in[0];   // (4,256,512)
    const float* dec = (const float*)d_in[1];   // (4,96,512)
    const float* W1  = (const float*)d_in[2];   // (1024,512)
    const float* b1  = (const float*)d_in[3];   // (512,)
    const float* W2  = (const float*)d_in[4];   // (512,1024)
    float* out = (float*)d_out;                 // (4,256,96,1024) f32

    char* ws = (char*)d_ws;
    float* he = (float*)(ws);                               // 1024x512 f32 (b1 folded)
    float* hd = (float*)(ws + 2097152);                     //  384x512 f32
    unsigned short* Wet = (unsigned short*)(ws + 2883584);  // 512x512 bf16 swz
    unsigned short* Wdt = (unsigned short*)(ws + 3407872);  // 512x512 bf16 swz
    unsigned short* W2t = (unsigned short*)(ws + 3932160);  // 1024x512 bf16 swz

    transpose_all<<<dim3(8, 16, 3), 256, 0, stream>>>(W1, W2, Wet, Wdt, W2t);
    gemm_small<<<dim3(11, 4), 256, 0, stream>>>(enc, dec, Wet, Wdt, b1, he, hd);
    joint_fused<<<dim3(1536, 2), 512, 0, stream>>>(he, hd, W2t, out);
}